// Round 7
// baseline (254.961 us; speedup 1.0000x reference)
//
#include <hip/hip_runtime.h>

#define F        128     // feature width
#define NPB      128     // nodes per bucket
#define NPBS     7
#define NBMAX    1024    // max buckets -> n_nodes <= 131072 (and < 2^20 packing)
#define CHMAX    2048    // edges per sort chunk
#define NBLKMAX  1024    // max chunks -> n_edges <= 2,097,152
#define ECAP     2560    // bucket edge cap (mean 2046 @ E/N=16, +11 sigma)
#define SRTSZ    3456    // ECAP + NPB*7 (8-aligned CSR padding)
#define OVFCAP   32768   // global spill list (cold correctness path)
#define BR       64      // fallback GEMM tile rows
#define KC       32      // fallback GEMM k-chunk

typedef short bf16x8 __attribute__((ext_vector_type(8)));
typedef float f32x4  __attribute__((ext_vector_type(4)));

__device__ __forceinline__ unsigned short f32_to_bf16_rne(float x) {
    unsigned u = __float_as_uint(x);
    u += 0x7fffu + ((u >> 16) & 1u);
    return (unsigned short)(u >> 16);
}

// ---------------------------------------------------------------------------
// Kernel 0: convert W fp32 -> bf16 (64 KB only).
// ---------------------------------------------------------------------------
__global__ __launch_bounds__(256) void conv_w_kernel(
        const float* __restrict__ Wf, unsigned short* __restrict__ Wb, int n4) {
    int i = blockIdx.x * blockDim.x + threadIdx.x;
    if (i < n4) {
        float4 v = *(const float4*)(Wf + 4 * (long)i);
        ushort4 o;
        o.x = f32_to_bf16_rne(v.x);
        o.y = f32_to_bf16_rne(v.y);
        o.z = f32_to_bf16_rne(v.z);
        o.w = f32_to_bf16_rne(v.w);
        *(ushort4*)(Wb + 4 * (long)i) = o;
    }
}

// ---------------------------------------------------------------------------
// Kernel 1 v2: h' = h @ W^T via MFMA bf16, A staged through LDS.
// Cross-round accounting exposed v1 at ~65us: its A-loads hit 16 different
// 512B-strided rows per instruction (16-line scatter, latency-bound).  v2:
// block loads a 64x128 fp32 tile with PERFECTLY coalesced float4 reads
// (thread -> consecutive 16B), converts to bf16, stores to LDS (row stride
// 272B -> fragment ds_read_b128 lands 2-way bank aliased = free), then each
// of 4 waves reads its MFMA fragments from LDS.  B (Wb, 32KB) stays L2-hot.
// C layout (measured m89/m91): col=lane&15, row=quad*4+reg.
// ---------------------------------------------------------------------------
__global__ __launch_bounds__(256) void gemm_h_kernel(
        const float* __restrict__ h,
        const unsigned short* __restrict__ Wb,
        unsigned short* __restrict__ hp,          // [n+1][128] bf16 (row n = zeros)
        int n_rows) {
    __shared__ unsigned short a_lds[64][136];     // +8 pad -> 272B row stride
    const int tid = threadIdx.x;
    const int r0 = blockIdx.x * 64;
    if (r0 >= n_rows) return;

    #pragma unroll 4
    for (int k = 0; k < 32; ++k) {                // 8192 float4s, coalesced
        int idx = k * 256 + tid;
        int row = idx >> 5;                       // 32 float4 per 128-col row
        int c4 = idx & 31;
        int grow = min(r0 + row, n_rows - 1);
        float4 v = *(const float4*)(h + (long)grow * F + c4 * 4);
        ushort4 o;
        o.x = f32_to_bf16_rne(v.x);
        o.y = f32_to_bf16_rne(v.y);
        o.z = f32_to_bf16_rne(v.z);
        o.w = f32_to_bf16_rne(v.w);
        *(ushort4*)&a_lds[row][c4 * 4] = o;
    }
    __syncthreads();

    const int wv = tid >> 6;
    const int lane = tid & 63;
    const int mn = lane & 15;
    const int quad = lane >> 4;
    const int m0 = r0 + wv * 16;
    if (m0 >= n_rows) return;                     // after the sync; no more syncs

    bf16x8 afr[4];
    #pragma unroll
    for (int kk = 0; kk < 4; ++kk)
        afr[kk] = *(const bf16x8*)&a_lds[wv * 16 + mn][kk * 32 + quad * 8];

    f32x4 acc[8];
    #pragma unroll
    for (int t = 0; t < 8; ++t) acc[t] = (f32x4){0.f, 0.f, 0.f, 0.f};

    #pragma unroll
    for (int kk = 0; kk < 4; ++kk) {
        #pragma unroll
        for (int t = 0; t < 8; ++t) {
            const unsigned short* wp = Wb + (long)(t * 16 + mn) * F + kk * 32 + quad * 8;
            bf16x8 bfr = *(const bf16x8*)wp;
            acc[t] = __builtin_amdgcn_mfma_f32_16x16x32_bf16(afr[kk], bfr, acc[t], 0, 0, 0);
        }
    }

    #pragma unroll
    for (int t = 0; t < 8; ++t) {
        const int col = t * 16 + mn;
        #pragma unroll
        for (int r = 0; r < 4; ++r) {
            const int orow = m0 + quad * 4 + r;
            if (orow < n_rows)
                hp[(long)orow * F + col] = f32_to_bf16_rne(acc[t][r]);
        }
    }
}

// ---------------------------------------------------------------------------
// Kernel A1 (count): per-chunk bucket histogram + LOCAL exclusive offsets,
// both written as coalesced rows.  No scattered writes anywhere (r5 lesson:
// per-(block,bucket) 4B scattered stores/RMW = the line-RMW wall in
// miniature; scattered READS are overlappable and cheap, scattered WRITES
// are not).  The scatter kernel will re-read lexcl instead of recomputing
// hist+scan (deletes 2 of its 5 phases).
// ---------------------------------------------------------------------------
__global__ __launch_bounds__(512) void count_kernel(
        const int* __restrict__ dst,
        int* __restrict__ cnt,                     // [NBLK][NB] row-coalesced
        int* __restrict__ lexcl,                   // [NBLK][NB] row-coalesced
        int n_edges, int NB) {
    __shared__ int hist[NBMAX];
    __shared__ int wsum[8];
    const int tid = threadIdx.x;
    const int lane = tid & 63;
    const int w = tid >> 6;
    const int lo = blockIdx.x * CHMAX;
    const int hi = min(n_edges, lo + CHMAX);

    for (int i = tid; i < NB; i += 512) hist[i] = 0;
    __syncthreads();
    for (int i = lo + tid; i < hi; i += 512)
        atomicAdd(&hist[((unsigned)dst[i]) >> NPBS], 1);
    __syncthreads();

    int* crow = cnt + (long)blockIdx.x * NB;
    int* erow = lexcl + (long)blockIdx.x * NB;
    int carry = 0;
    for (int c0 = 0; c0 < NB; c0 += 512) {
        const int idx = c0 + tid;
        const int own = (idx < NB) ? hist[idx] : 0;
        int v = own;
        #pragma unroll
        for (int d = 1; d < 64; d <<= 1) { int u = __shfl_up(v, d); if (lane >= d) v += u; }
        if (lane == 63) wsum[w] = v;
        __syncthreads();
        if (w == 0) {
            int s = (lane < 8) ? wsum[lane] : 0;
            #pragma unroll
            for (int d = 1; d < 8; d <<= 1) { int u = __shfl_up(s, d); if (lane >= d) s += u; }
            if (lane < 8) wsum[lane] = s;
        }
        __syncthreads();
        const int ex = v - own + ((w > 0) ? wsum[w - 1] : 0) + carry;
        if (idx < NB) { crow[idx] = own; erow[idx] = ex; }
        carry += wsum[7];
        __syncthreads();
    }
}

// ---------------------------------------------------------------------------
// Kernel A2 (scan): per-bucket exclusive prefix over chunks.  Reads cnt
// COLUMNS (scattered 4B reads: L2-shared lines, latency overlapped — fine),
// writes gbase as coalesced ROWS.  Zero scattered writes.
// ---------------------------------------------------------------------------
__global__ __launch_bounds__(256) void scan_kernel(
        const int* __restrict__ cnt,               // [NBLK][NB]
        int* __restrict__ gbase,                   // [NB][NBLK] row-coalesced
        int* __restrict__ gcnt,                    // [NB]
        int NB, int NBLK) {
    __shared__ int wsum[4];
    const int b = blockIdx.x;
    const int tid = threadIdx.x;
    const int lane = tid & 63;
    const int w = tid >> 6;
    int* grow = gbase + (long)b * NBLK;
    int carry = 0;
    for (int c0 = 0; c0 < NBLK; c0 += 256) {
        const int c = c0 + tid;
        const int own = (c < NBLK) ? cnt[(long)c * NB + b] : 0;   // scattered read
        int v = own;
        #pragma unroll
        for (int d = 1; d < 64; d <<= 1) { int u = __shfl_up(v, d); if (lane >= d) v += u; }
        if (lane == 63) wsum[w] = v;
        __syncthreads();
        if (w == 0) {
            int s = (lane < 4) ? wsum[lane] : 0;
            #pragma unroll
            for (int d = 1; d < 4; d <<= 1) { int u = __shfl_up(s, d); if (lane >= d) s += u; }
            if (lane < 4) wsum[lane] = s;
        }
        __syncthreads();
        const int ex = v - own + ((w > 0) ? wsum[w - 1] : 0) + carry;
        if (c < NBLK) grow[c] = ex;                // coalesced write
        carry += wsum[3];
        __syncthreads();
    }
    if (tid == 0) gcnt[b] = carry;
}

// ---------------------------------------------------------------------------
// Kernel A3 (scatter): register-stage chunk, LDS counting-sort using the
// PRECOMPUTED lexcl (no hist, no scan), flush run-coalesced into
// bucket-contiguous ebuf.  gbase column read is L2-hit scattered-read.
// ---------------------------------------------------------------------------
__global__ __launch_bounds__(512) void scatter_kernel(
        const int* __restrict__ src,
        const int* __restrict__ dst,
        const int* __restrict__ lexcl,             // [NBLK][NB]
        const int* __restrict__ gbase,             // [NB][NBLK]
        int* __restrict__ ebuf,                    // [NB * ECAP]
        int* __restrict__ ovf,                     // [1 + 2*OVFCAP], ovf[0]=0
        int n_edges, int NB, int NBLK) {
    __shared__ int cursor[NBMAX];
    __shared__ int dlt[NBMAX];
    __shared__ int sval[CHMAX];
    __shared__ unsigned short sbkt[CHMAX];
    const int tid = threadIdx.x;
    const int ch = blockIdx.x;
    const int lo = ch * CHMAX;
    const int hi = min(n_edges, lo + CHMAX);
    const int len = hi - lo;

    int dd[4], ss[4];
    #pragma unroll
    for (int k = 0; k < 4; ++k) {
        int i = lo + k * 512 + tid;
        bool ok = i < hi;
        dd[k] = ok ? dst[i] : -1;
        ss[k] = ok ? src[i] : 0;
    }
    const int* erow = lexcl + (long)ch * NB;
    for (int i = tid; i < NB; i += 512) {
        int lex = erow[i];                         // coalesced
        cursor[i] = lex;
        dlt[i] = gbase[(long)i * NBLK + ch] - lex; // scattered read, L2-shared
    }
    __syncthreads();

    #pragma unroll
    for (int k = 0; k < 4; ++k)
        if (dd[k] >= 0) {
            int b = ((unsigned)dd[k]) >> NPBS;
            int p = atomicAdd(&cursor[b], 1);      // ds_add_rtn_u32, p < len
            sval[p] = ((dd[k] & (NPB - 1)) << 20) | ss[k];
            sbkt[p] = (unsigned short)b;
        }
    __syncthreads();

    for (int i = tid; i < len; i += 512) {
        int vv = sval[i];
        int b = sbkt[i];
        int slot = i + dlt[b];
        if (slot < ECAP) {
            ebuf[(long)b * ECAP + slot] = vv;      // run-coalesced
        } else {                                   // cold correctness path
            int q = atomicAdd(&ovf[0], 1);
            if (q < OVFCAP) {
                ovf[1 + 2 * q] = (b << NPBS) | (vv >> 20);
                ovf[2 + 2 * q] = vv & 0xFFFFF;
            }
        }
    }
}

// ---------------------------------------------------------------------------
// Kernel B: per-bucket CSR + register accumulation + fused bias+relu.
// NPB=128, 512 threads (8 waves x 16 nodes): 782 blocks at 4 blocks/CU ->
// ~76% occupancy (r5: 391x16-wave blocks = 48%; r6: slice-concat = worse).
// ebuf register-staged (one coalesced pass); CSR segments 8-ALIGNED and
// zero-row padded -> mask-free inner loop: per 8 edges = 2 ds_read_b128 +
// 8 coalesced 256B row loads + 16 unpack + 16 fadd.  Each out row written
// exactly once.
// ---------------------------------------------------------------------------
__global__ __launch_bounds__(512) void bucket_gather_kernel(
        const unsigned short* __restrict__ hp,     // [n_nodes+1][128], row n = 0
        const int* __restrict__ gcnt,
        const int* __restrict__ ebuf,
        const int* __restrict__ ovf,
        const float* __restrict__ bias,
        float* __restrict__ out,
        int n_nodes) {
    __shared__ int hist[NPB];
    __shared__ int ofs[NPB + 1];
    __shared__ int cur[NPB];
    __shared__ __align__(16) int srt[SRTSZ];
    __shared__ int wsum[8];
    const int b = blockIdx.x;
    const int tid = threadIdx.x;
    const int lane = tid & 63;
    const int w = tid >> 6;
    const int cnt = min(gcnt[b], ECAP);
    const int novf = ovf[0];
    const int* eb = ebuf + (long)b * ECAP;

    int ev[5];                                     // 5*512 = 2560 = ECAP
    #pragma unroll
    for (int k = 0; k < 5; ++k) {
        int i = k * 512 + tid;
        ev[k] = (i < cnt) ? eb[i] : -1;
    }
    if (tid < NPB) hist[tid] = 0;
    __syncthreads();

    #pragma unroll
    for (int k = 0; k < 5; ++k)
        if (ev[k] >= 0) atomicAdd(&hist[((unsigned)ev[k]) >> 20], 1);
    __syncthreads();

    // scan 8-PADDED degrees (threads >=128 contribute 0) + sentinel init
    {
        const int own = (tid < NPB) ? hist[tid] : 0;
        const int pd = (own + 7) & ~7;
        int v = pd;
        #pragma unroll
        for (int d = 1; d < 64; d <<= 1) { int u = __shfl_up(v, d); if (lane >= d) v += u; }
        if (lane == 63) wsum[w] = v;
        __syncthreads();
        if (w == 0) {
            int s = (lane < 8) ? wsum[lane] : 0;
            #pragma unroll
            for (int d = 1; d < 8; d <<= 1) { int u = __shfl_up(s, d); if (lane >= d) s += u; }
            if (lane < 8) wsum[lane] = s;
        }
        __syncthreads();
        const int ex = v - pd + ((w > 0) ? wsum[w - 1] : 0);
        if (tid < NPB) { ofs[tid] = ex; cur[tid] = ex; }
        if (tid == NPB - 1) ofs[NPB] = ex + pd;
        for (int i = tid; i < SRTSZ; i += 512) srt[i] = n_nodes;  // zero-row id
    }
    __syncthreads();

    #pragma unroll
    for (int k = 0; k < 5; ++k)
        if (ev[k] >= 0) {
            int p = atomicAdd(&cur[((unsigned)ev[k]) >> 20], 1);
            srt[p] = ev[k] & 0xFFFFF;
        }
    __syncthreads();

    const unsigned lo4 = lane << 2;                // this lane's dword in a row
    const float2 bv = *(const float2*)(bias + (lane << 1));
    for (int nl = w; nl < NPB; nl += 8) {
        const int n = (b << NPBS) + nl;
        if (n >= n_nodes) break;
        const int beg = ofs[nl];
        const int pend = ofs[nl + 1];              // 8-aligned end

        float ax = 0.f, ay = 0.f;
        for (int i = beg; i < pend; i += 8) {
            const int4 ia = *(const int4*)&srt[i];       // ds_read_b128
            const int4 ib = *(const int4*)&srt[i + 4];   // ds_read_b128
            int sid[8] = {ia.x, ia.y, ia.z, ia.w, ib.x, ib.y, ib.z, ib.w};
            unsigned vv[8];
            #pragma unroll
            for (int j = 0; j < 8; ++j)
                vv[j] = *(const unsigned*)((const char*)hp +
                                           (((unsigned)sid[j] << 8) | lo4));
            #pragma unroll
            for (int j = 0; j < 8; ++j) {
                ax += __uint_as_float(vv[j] << 16);
                ay += __uint_as_float(vv[j] & 0xffff0000u);
            }
        }

        if (novf > 0) {                            // cold spill drain
            int ne = min(novf, OVFCAP);
            for (int k = 0; k < ne; ++k) {
                if (ovf[1 + 2 * k] == n) {
                    unsigned u = *(const unsigned*)((const char*)hp +
                                   (((unsigned)ovf[2 + 2 * k] << 8) | lo4));
                    ax += __uint_as_float(u << 16);
                    ay += __uint_as_float(u & 0xffff0000u);
                }
            }
        }

        float rx = fmaxf(ax + bv.x, 0.f);
        float ry = fmaxf(ay + bv.y, 0.f);
        *(float2*)((char*)out + (((unsigned)n << 9) | (lane << 3))) =
            make_float2(rx, ry);
    }
}

// ---------------------------------------------------------------------------
// Fallback tier (tiny ws or oversize graph): atomic scatter + fp32 GEMM.
// ---------------------------------------------------------------------------
__global__ void scatter_add_kernel(const float* __restrict__ h,
                                   const int* __restrict__ src,
                                   const int* __restrict__ dst,
                                   float* __restrict__ agg,
                                   long total) {
    long stride = (long)gridDim.x * blockDim.x;
    for (long i = (long)blockIdx.x * blockDim.x + threadIdx.x; i < total; i += stride) {
        int e    = (int)(i >> 5);
        int lane = (int)(i & 31);
        int s = src[e];
        int d = dst[e];
        float4 v = *(const float4*)(h + (long)s * F + (lane << 2));
        float* o = agg + (long)d * F + (lane << 2);
        unsafeAtomicAdd(o + 0, v.x);
        unsafeAtomicAdd(o + 1, v.y);
        unsafeAtomicAdd(o + 2, v.z);
        unsafeAtomicAdd(o + 3, v.w);
    }
}

__global__ __launch_bounds__(256) void gemm_bias_relu_inplace(
        float* __restrict__ out,
        const float* __restrict__ W,
        const float* __restrict__ bias,
        int n_rows) {
    __shared__ __align__(16) float a_t[KC][BR + 4];
    __shared__ __align__(16) float w_t[KC][F + 4];
    const int tid = threadIdx.x;
    const int tx = tid & 15;
    const int ty = tid >> 4;
    const int row0 = blockIdx.x * BR;
    float acc[4][8];
    #pragma unroll
    for (int i = 0; i < 4; ++i)
        #pragma unroll
        for (int j = 0; j < 8; ++j) acc[i][j] = 0.f;
    for (int kc = 0; kc < F; kc += KC) {
        #pragma unroll
        for (int p = 0; p < 2; ++p) {
            int q = tid + p * 256, r = q >> 3, kq = q & 7;
            int row = row0 + r;
            float4 v = make_float4(0.f, 0.f, 0.f, 0.f);
            if (row < n_rows) v = *(const float4*)(out + (long)row * F + kc + (kq << 2));
            a_t[kq * 4 + 0][r] = v.x; a_t[kq * 4 + 1][r] = v.y;
            a_t[kq * 4 + 2][r] = v.z; a_t[kq * 4 + 3][r] = v.w;
        }
        #pragma unroll
        for (int p = 0; p < 4; ++p) {
            int q = tid + p * 256, j = q >> 3, kq = q & 7;
            float4 v = *(const float4*)(W + (long)j * F + kc + (kq << 2));
            w_t[kq * 4 + 0][j] = v.x; w_t[kq * 4 + 1][j] = v.y;
            w_t[kq * 4 + 2][j] = v.z; w_t[kq * 4 + 3][j] = v.w;
        }
        __syncthreads();
        #pragma unroll
        for (int k = 0; k < KC; ++k) {
            float4 av = *(const float4*)&a_t[k][ty << 2];
            float4 w0 = *(const float4*)&w_t[k][tx << 2];
            float4 w1 = *(const float4*)&w_t[k][64 + (tx << 2)];
            float a4[4] = {av.x, av.y, av.z, av.w};
            float wv[8] = {w0.x, w0.y, w0.z, w0.w, w1.x, w1.y, w1.z, w1.w};
            #pragma unroll
            for (int i = 0; i < 4; ++i)
                #pragma unroll
                for (int j = 0; j < 8; ++j) acc[i][j] += a4[i] * wv[j];
        }
        __syncthreads();
    }
    float4 b0 = *(const float4*)(bias + (tx << 2));
    float4 b1 = *(const float4*)(bias + 64 + (tx << 2));
    #pragma unroll
    for (int i = 0; i < 4; ++i) {
        int row = row0 + (ty << 2) + i;
        if (row < n_rows) {
            float4 r0, r1;
            r0.x = fmaxf(acc[i][0] + b0.x, 0.f); r0.y = fmaxf(acc[i][1] + b0.y, 0.f);
            r0.z = fmaxf(acc[i][2] + b0.z, 0.f); r0.w = fmaxf(acc[i][3] + b0.w, 0.f);
            r1.x = fmaxf(acc[i][4] + b1.x, 0.f); r1.y = fmaxf(acc[i][5] + b1.y, 0.f);
            r1.z = fmaxf(acc[i][6] + b1.z, 0.f); r1.w = fmaxf(acc[i][7] + b1.w, 0.f);
            *(float4*)(out + (long)row * F + (tx << 2)) = r0;
            *(float4*)(out + (long)row * F + 64 + (tx << 2)) = r1;
        }
    }
}

extern "C" void kernel_launch(void* const* d_in, const int* in_sizes, int n_in,
                              void* d_out, int out_size, void* d_ws, size_t ws_size,
                              hipStream_t stream) {
    const float* h   = (const float*)d_in[0];
    const int*   src = (const int*)d_in[1];
    const int*   dst = (const int*)d_in[2];
    const float* W   = (const float*)d_in[3];
    const float* b   = (const float*)d_in[4];
    float* out = (float*)d_out;

    const int n_nodes = in_sizes[0] / F;
    const int n_edges = in_sizes[1];
    const int NB   = (n_nodes + NPB - 1) >> NPBS;
    const int NBLK = (n_edges + CHMAX - 1) / CHMAX;

    // ws layout: gcnt | ovf | cnt | lexcl | gbase | ebuf | hp (+1 zero row) | Wb
    auto al16 = [](size_t x) { return (x + 15) & ~(size_t)15; };
    const size_t off_gcnt = 0;
    const size_t off_ovf  = al16((size_t)NB * 4);
    const size_t off_cnt  = al16(off_ovf + 4 + (size_t)OVFCAP * 8);
    const size_t off_lex  = al16(off_cnt + (size_t)NBLK * NB * 4);
    const size_t off_gb   = al16(off_lex + (size_t)NBLK * NB * 4);
    const size_t off_ebuf = al16(off_gb + (size_t)NB * NBLK * 4);
    const size_t off_hp   = al16(off_ebuf + (size_t)NB * ECAP * 4);
    const size_t off_wb   = al16(off_hp + (size_t)(n_nodes + 1) * F * 2);
    const size_t need     = off_wb + (size_t)F * F * 2;

    if (ws_size >= need && n_nodes > 0 && NB <= NBMAX && NBLK <= NBLKMAX) {
        int* gcnt  = (int*)((char*)d_ws + off_gcnt);
        int* ovf   = (int*)((char*)d_ws + off_ovf);
        int* cnt   = (int*)((char*)d_ws + off_cnt);
        int* lexcl = (int*)((char*)d_ws + off_lex);
        int* gbase = (int*)((char*)d_ws + off_gb);
        int* ebuf  = (int*)((char*)d_ws + off_ebuf);
        unsigned short* hp = (unsigned short*)((char*)d_ws + off_hp);
        unsigned short* Wb = (unsigned short*)((char*)d_ws + off_wb);

        hipMemsetAsync(ovf, 0, 4, stream);
        hipMemsetAsync(hp + (size_t)n_nodes * F, 0, (size_t)F * 2, stream);  // zero row

        conv_w_kernel<<<(F * F / 4 + 255) / 256, 256, 0, stream>>>(W, Wb, F * F / 4);

        gemm_h_kernel<<<(n_nodes + 63) / 64, 256, 0, stream>>>(h, Wb, hp, n_nodes);

        if (NBLK > 0)
            count_kernel<<<NBLK, 512, 0, stream>>>(dst, cnt, lexcl, n_edges, NB);

        scan_kernel<<<NB, 256, 0, stream>>>(cnt, gbase, gcnt, NB, NBLK);

        if (NBLK > 0)
            scatter_kernel<<<NBLK, 512, 0, stream>>>(src, dst, lexcl, gbase,
                                                     ebuf, ovf, n_edges, NB, NBLK);

        bucket_gather_kernel<<<NB, 512, 0, stream>>>(hp, gcnt, ebuf, ovf, b,
                                                     out, n_nodes);
    } else {
        hipMemsetAsync(out, 0, (size_t)out_size * sizeof(float), stream);
        scatter_add_kernel<<<16384, 256, 0, stream>>>(
            h, src, dst, out, (long)n_edges * 32);
        const int gblocks = (n_nodes + BR - 1) / BR;
        gemm_bias_relu_inplace<<<gblocks, 256, 0, stream>>>(out, W, b, n_nodes);
    }
}

// Round 8
// 224.264 us; speedup vs baseline: 1.1369x; 1.1369x over previous
//
#include <hip/hip_runtime.h>

#define F      128       // feature width
#define NPB    256       // nodes per bucket
#define NPBS   8
#define NBMAX  512       // max buckets (scan width); n_nodes <= 131072 < 2^20
#define ECAP   5120      // bucket edge cap (mean 4096 @ E/N=16, +16 sigma)
#define CHMAX  4096      // edges per sort chunk
#define CH_PT  4         // CHMAX / 1024
#define OVFCAP 32768     // spill-list capacity (cold correctness path)
#define BR     64        // rows per fp32-GEMM block tile (fallback)
#define KC     32        // k-chunk (fallback GEMM)

typedef short bf16x8 __attribute__((ext_vector_type(8)));
typedef float f32x4  __attribute__((ext_vector_type(4)));

__device__ __forceinline__ unsigned short f32_to_bf16_rne(float x) {
    unsigned u = __float_as_uint(x);
    u += 0x7fffu + ((u >> 16) & 1u);
    return (unsigned short)(u >> 16);
}

// ---------------------------------------------------------------------------
// Kernel 0: convert W fp32 -> bf16 (64 KB only).
// ---------------------------------------------------------------------------
__global__ __launch_bounds__(256) void conv_w_kernel(
        const float* __restrict__ Wf, unsigned short* __restrict__ Wb, int n4) {
    int i = blockIdx.x * blockDim.x + threadIdx.x;
    if (i < n4) {
        float4 v = *(const float4*)(Wf + 4 * (long)i);
        ushort4 o;
        o.x = f32_to_bf16_rne(v.x);
        o.y = f32_to_bf16_rne(v.y);
        o.z = f32_to_bf16_rne(v.z);
        o.w = f32_to_bf16_rne(v.w);
        *(ushort4*)(Wb + 4 * (long)i) = o;
    }
}

// ---------------------------------------------------------------------------
// Kernel 1 v2 (FIXED): h' = h @ W^T via MFMA bf16, A staged through LDS.
// r7 bug: staging loop ran k<32 (8192 float4) for a 2048-float4 tile -> 4x
// global over-read + OOB LDS writes (dropped).  Correct k<8.  Loads are
// perfectly coalesced float4 rows; fragments read from LDS (272B row stride
// -> 2-way bank aliasing = free).  B (Wb, 32KB) stays L2-hot.
// C layout (measured m89/m91): col=lane&15, row=quad*4+reg.
// ---------------------------------------------------------------------------
__global__ __launch_bounds__(256) void gemm_h_kernel(
        const float* __restrict__ h,
        const unsigned short* __restrict__ Wb,
        unsigned short* __restrict__ hp,          // [n][128] bf16 out
        int n_rows) {
    __shared__ unsigned short a_lds[64][136];     // +8 pad -> 272B row stride
    const int tid = threadIdx.x;
    const int r0 = blockIdx.x * 64;
    if (r0 >= n_rows) return;

    #pragma unroll
    for (int k = 0; k < 8; ++k) {                 // 2048 float4s = 64x128 fp32
        int idx = k * 256 + tid;
        int row = idx >> 5;                       // 32 float4 per 128-col row
        int c4 = idx & 31;
        int grow = min(r0 + row, n_rows - 1);
        float4 v = *(const float4*)(h + (long)grow * F + c4 * 4);
        ushort4 o;
        o.x = f32_to_bf16_rne(v.x);
        o.y = f32_to_bf16_rne(v.y);
        o.z = f32_to_bf16_rne(v.z);
        o.w = f32_to_bf16_rne(v.w);
        *(ushort4*)&a_lds[row][c4 * 4] = o;
    }
    __syncthreads();

    const int wv = tid >> 6;
    const int lane = tid & 63;
    const int mn = lane & 15;
    const int quad = lane >> 4;
    const int m0 = r0 + wv * 16;
    if (m0 >= n_rows) return;                     // after the only sync

    bf16x8 afr[4];
    #pragma unroll
    for (int kk = 0; kk < 4; ++kk)
        afr[kk] = *(const bf16x8*)&a_lds[wv * 16 + mn][kk * 32 + quad * 8];

    f32x4 acc[8];
    #pragma unroll
    for (int t = 0; t < 8; ++t) acc[t] = (f32x4){0.f, 0.f, 0.f, 0.f};

    #pragma unroll
    for (int kk = 0; kk < 4; ++kk) {
        #pragma unroll
        for (int t = 0; t < 8; ++t) {
            const unsigned short* wp = Wb + (long)(t * 16 + mn) * F + kk * 32 + quad * 8;
            bf16x8 bfr = *(const bf16x8*)wp;
            acc[t] = __builtin_amdgcn_mfma_f32_16x16x32_bf16(afr[kk], bfr, acc[t], 0, 0, 0);
        }
    }

    #pragma unroll
    for (int t = 0; t < 8; ++t) {
        const int col = t * 16 + mn;
        #pragma unroll
        for (int r = 0; r < 4; ++r) {
            const int orow = m0 + quad * 4 + r;
            if (orow < n_rows)
                hp[(long)orow * F + col] = f32_to_bf16_rne(acc[t][r]);
        }
    }
}

// ---------------------------------------------------------------------------
// Kernel A1 (r5 verbatim): per-chunk bucket histogram -> cntmat rows.
// ---------------------------------------------------------------------------
__global__ __launch_bounds__(1024) void count_kernel(
        const int* __restrict__ dst,
        int* __restrict__ cntmat,                  // [NBLK][NB]
        int n_edges, int NB) {
    __shared__ int hist[NBMAX];
    const int tid = threadIdx.x;
    const int lo = blockIdx.x * CHMAX;
    const int hi = min(n_edges, lo + CHMAX);
    for (int i = tid; i < NB; i += 1024) hist[i] = 0;
    __syncthreads();
    for (int i = lo + tid; i < hi; i += 1024)
        atomicAdd(&hist[((unsigned)dst[i]) >> NPBS], 1);
    __syncthreads();
    int* row = cntmat + (long)blockIdx.x * NB;
    for (int i = tid; i < NB; i += 1024) row[i] = hist[i];
}

// ---------------------------------------------------------------------------
// Kernel A2 (r5 verbatim): per-bucket exclusive prefix over chunks + gcnt.
// ---------------------------------------------------------------------------
__global__ __launch_bounds__(256) void scan_kernel(
        int* __restrict__ cntmat, int* __restrict__ gcnt, int NB, int NBLK) {
    __shared__ int wsum[4];
    const int b = blockIdx.x;
    const int tid = threadIdx.x;
    const int lane = tid & 63;
    const int w = tid >> 6;
    int carry = 0;
    for (int c0 = 0; c0 < NBLK; c0 += 256) {
        const int blk = c0 + tid;
        const int own = (blk < NBLK) ? cntmat[(long)blk * NB + b] : 0;
        int v = own;
        #pragma unroll
        for (int d = 1; d < 64; d <<= 1) { int u = __shfl_up(v, d); if (lane >= d) v += u; }
        if (lane == 63) wsum[w] = v;
        __syncthreads();
        if (w == 0) {
            int s = (lane < 4) ? wsum[lane] : 0;
            #pragma unroll
            for (int d = 1; d < 4; d <<= 1) { int u = __shfl_up(s, d); if (lane >= d) s += u; }
            if (lane < 4) wsum[lane] = s;
        }
        __syncthreads();
        const int excl = v - own + ((w > 0) ? wsum[w - 1] : 0) + carry;
        if (blk < NBLK) cntmat[(long)blk * NB + b] = excl;
        carry += wsum[3];
        __syncthreads();
    }
    if (tid == 0) gcnt[b] = carry;
}

// ---------------------------------------------------------------------------
// Kernel A3 (r5 verbatim): register-staged counting sort of a 4096-edge
// chunk + coalesced run flush into bucket-segmented ebuf.
// ---------------------------------------------------------------------------
__global__ __launch_bounds__(1024) void scatter_kernel(
        const int* __restrict__ src,
        const int* __restrict__ dst,
        const int* __restrict__ cntmat,
        int* __restrict__ ebuf,                    // [NB * ECAP]
        int* __restrict__ ovf,                     // [1 + 2*OVFCAP], ovf[0]=0
        int n_edges, int NB) {
    __shared__ int hist[NBMAX];
    __shared__ int dlt[NBMAX];
    __shared__ int cursor[NBMAX];
    __shared__ int sval[CHMAX];
    __shared__ unsigned short sbkt[CHMAX];
    __shared__ int wsum[16];
    const int tid = threadIdx.x;
    const int lane = tid & 63;
    const int w = tid >> 6;
    const int lo = blockIdx.x * CHMAX;
    const int hi = min(n_edges, lo + CHMAX);
    const int len = hi - lo;

    int dd[CH_PT], ss[CH_PT];
    #pragma unroll
    for (int k = 0; k < CH_PT; ++k) {
        int i = lo + k * 1024 + tid;
        bool ok = i < hi;
        dd[k] = ok ? dst[i] : -1;
        ss[k] = ok ? src[i] : 0;
    }
    for (int i = tid; i < NB; i += 1024) hist[i] = 0;
    __syncthreads();

    #pragma unroll
    for (int k = 0; k < CH_PT; ++k)
        if (dd[k] >= 0) atomicAdd(&hist[((unsigned)dd[k]) >> NPBS], 1);
    __syncthreads();

    const int own = (tid < NB) ? hist[tid] : 0;
    int v = own;
    #pragma unroll
    for (int d = 1; d < 64; d <<= 1) { int u = __shfl_up(v, d); if (lane >= d) v += u; }
    if (lane == 63) wsum[w] = v;
    __syncthreads();
    if (w == 0) {
        int s = (lane < 16) ? wsum[lane] : 0;
        #pragma unroll
        for (int d = 1; d < 16; d <<= 1) { int u = __shfl_up(s, d); if (lane >= d) s += u; }
        if (lane < 16) wsum[lane] = s;
    }
    __syncthreads();
    if (tid < NB) {
        const int excl = v - own + ((w > 0) ? wsum[w - 1] : 0);
        dlt[tid] = cntmat[(long)blockIdx.x * NB + tid] - excl;
        cursor[tid] = excl;
    }
    __syncthreads();

    #pragma unroll
    for (int k = 0; k < CH_PT; ++k)
        if (dd[k] >= 0) {
            int b = ((unsigned)dd[k]) >> NPBS;
            int p = atomicAdd(&cursor[b], 1);      // ds_add_rtn_u32
            sval[p] = ((dd[k] & (NPB - 1)) << 20) | ss[k];
            sbkt[p] = (unsigned short)b;
        }
    __syncthreads();

    for (int i = tid; i < len; i += 1024) {
        int vv = sval[i];
        int b = sbkt[i];
        int slot = i + dlt[b];
        if (slot < ECAP) {
            ebuf[(long)b * ECAP + slot] = vv;
        } else {                                   // cold correctness path
            int q = atomicAdd(&ovf[0], 1);
            if (q < OVFCAP) {
                ovf[1 + 2 * q] = (b << NPBS) | (vv >> 20);
                ovf[2 + 2 * q] = vv & 0xFFFFF;
            }
        }
    }
}

// ---------------------------------------------------------------------------
// Kernel B: r5 gather + DUAL-NODE interleave.  r7 evidence: gather is
// memory-LATENCY-bound (VALU 47->26% with no speedup; same FETCH).  At fixed
// occupancy the lever is loads-in-flight/wave: each wave now processes node
// pair (nl, nl+16) concurrently -> 16 independent 256B row loads in flight.
// Masked remainder (r5-style, proven); safe fallback index when one segment
// is empty.  1024 thr = 16 waves; NPB=256.
// ---------------------------------------------------------------------------
__global__ __launch_bounds__(1024) void bucket_gather_kernel(
        const unsigned short* __restrict__ hp,     // [n_nodes][128]
        const int* __restrict__ gcnt,
        const int* __restrict__ ebuf,
        const int* __restrict__ ovf,
        const float* __restrict__ bias,
        float* __restrict__ out,
        int n_nodes) {
    __shared__ int hist[NPB];
    __shared__ int ofs[NPB];
    __shared__ int cur[NPB];
    __shared__ int srt[ECAP];
    __shared__ int wsum[16];
    const int bkt = blockIdx.x;
    const int tid = threadIdx.x;
    const int lane = tid & 63;
    const int w = tid >> 6;
    const int cnt = min(gcnt[bkt], ECAP);
    const int novf = ovf[0];
    const int* eb = ebuf + (long)bkt * ECAP;

    int ev[5];                                     // 5*1024 = 5120 = ECAP
    #pragma unroll
    for (int k = 0; k < 5; ++k) {
        int i = k * 1024 + tid;
        ev[k] = (i < cnt) ? eb[i] : -1;
    }
    if (tid < NPB) hist[tid] = 0;
    __syncthreads();

    #pragma unroll
    for (int k = 0; k < 5; ++k)
        if (ev[k] >= 0) atomicAdd(&hist[((unsigned)ev[k]) >> 20], 1);
    __syncthreads();

    const int own = (tid < NPB) ? hist[tid] : 0;
    int v = own;
    #pragma unroll
    for (int d = 1; d < 64; d <<= 1) { int u = __shfl_up(v, d); if (lane >= d) v += u; }
    if (lane == 63) wsum[w] = v;
    __syncthreads();
    if (w == 0) {
        int s = (lane < 16) ? wsum[lane] : 0;
        #pragma unroll
        for (int d = 1; d < 16; d <<= 1) { int u = __shfl_up(s, d); if (lane >= d) s += u; }
        if (lane < 16) wsum[lane] = s;
    }
    __syncthreads();
    if (tid < NPB) {
        const int e = v - own + ((w > 0) ? wsum[w - 1] : 0);
        ofs[tid] = e;
        cur[tid] = e;
    }
    __syncthreads();

    #pragma unroll
    for (int k = 0; k < 5; ++k)
        if (ev[k] >= 0) {
            int p = atomicAdd(&cur[((unsigned)ev[k]) >> 20], 1);
            srt[p] = ev[k] & 0xFFFFF;
        }
    __syncthreads();

    const unsigned lo4 = lane << 2;                // this lane's dword in a row
    const float2 bv = *(const float2*)(bias + (lane << 1));
    for (int nl = w; nl < NPB; nl += 32) {         // pair (nl, nl+16)
        const int nA = (bkt << NPBS) + nl;
        const int nB = nA + 16;
        if (nA >= n_nodes) break;
        const int begA = ofs[nl];
        const int lenA = hist[nl];
        const int begB = ofs[nl + 16];
        const int lenB = hist[nl + 16];
        // safe fallback index for masked slots (only used when that side has
        // any valid edge OR the other side drives the loop)
        const int fbA = (lenA > 0) ? begA : begB;
        const int fbB = (lenB > 0) ? begB : begA;
        const int mx = max(lenA, lenB);

        float ax0 = 0.f, ay0 = 0.f, ax1 = 0.f, ay1 = 0.f;
        for (int i = 0; i < mx; i += 8) {          // 16 row loads in flight
            unsigned va[8], vb[8];
            bool la[8], lb[8];
            #pragma unroll
            for (int j = 0; j < 8; ++j) {
                la[j] = (i + j) < lenA;
                lb[j] = (i + j) < lenB;
                int sa = srt[la[j] ? begA + i + j : fbA];  // uniform -> bcast
                int sb = srt[lb[j] ? begB + i + j : fbB];
                va[j] = *(const unsigned*)((const char*)hp +
                                           (((unsigned)sa << 8) | lo4));
                vb[j] = *(const unsigned*)((const char*)hp +
                                           (((unsigned)sb << 8) | lo4));
            }
            #pragma unroll
            for (int j = 0; j < 8; ++j) {
                if (la[j]) {
                    ax0 += __uint_as_float(va[j] << 16);
                    ay0 += __uint_as_float(va[j] & 0xffff0000u);
                }
                if (lb[j]) {
                    ax1 += __uint_as_float(vb[j] << 16);
                    ay1 += __uint_as_float(vb[j] & 0xffff0000u);
                }
            }
        }

        if (novf > 0) {                            // cold spill drain
            int ne = min(novf, OVFCAP);
            for (int k = 0; k < ne; ++k) {
                int dd = ovf[1 + 2 * k];
                if (dd == nA || dd == nB) {
                    unsigned u = *(const unsigned*)((const char*)hp +
                                   (((unsigned)ovf[2 + 2 * k] << 8) | lo4));
                    float ux = __uint_as_float(u << 16);
                    float uy = __uint_as_float(u & 0xffff0000u);
                    if (dd == nA) { ax0 += ux; ay0 += uy; }
                    else          { ax1 += ux; ay1 += uy; }
                }
            }
        }

        float rx0 = fmaxf(ax0 + bv.x, 0.f);
        float ry0 = fmaxf(ay0 + bv.y, 0.f);
        *(float2*)((char*)out + (((unsigned)nA << 9) | (lane << 3))) =
            make_float2(rx0, ry0);
        if (nB < n_nodes) {
            float rx1 = fmaxf(ax1 + bv.x, 0.f);
            float ry1 = fmaxf(ay1 + bv.y, 0.f);
            *(float2*)((char*)out + (((unsigned)nB << 9) | (lane << 3))) =
                make_float2(rx1, ry1);
        }
    }
}

// ---------------------------------------------------------------------------
// Fallback tier (tiny ws or oversize graph): atomic scatter + fp32 GEMM.
// ---------------------------------------------------------------------------
__global__ void scatter_add_kernel(const float* __restrict__ h,
                                   const int* __restrict__ src,
                                   const int* __restrict__ dst,
                                   float* __restrict__ agg,
                                   long total) {
    long stride = (long)gridDim.x * blockDim.x;
    for (long i = (long)blockIdx.x * blockDim.x + threadIdx.x; i < total; i += stride) {
        int e    = (int)(i >> 5);
        int lane = (int)(i & 31);
        int s = src[e];
        int d = dst[e];
        float4 v = *(const float4*)(h + (long)s * F + (lane << 2));
        float* o = agg + (long)d * F + (lane << 2);
        unsafeAtomicAdd(o + 0, v.x);
        unsafeAtomicAdd(o + 1, v.y);
        unsafeAtomicAdd(o + 2, v.z);
        unsafeAtomicAdd(o + 3, v.w);
    }
}

__global__ __launch_bounds__(256) void gemm_bias_relu_inplace(
        float* __restrict__ out,
        const float* __restrict__ W,
        const float* __restrict__ bias,
        int n_rows) {
    __shared__ __align__(16) float a_t[KC][BR + 4];
    __shared__ __align__(16) float w_t[KC][F + 4];
    const int tid = threadIdx.x;
    const int tx = tid & 15;
    const int ty = tid >> 4;
    const int row0 = blockIdx.x * BR;
    float acc[4][8];
    #pragma unroll
    for (int i = 0; i < 4; ++i)
        #pragma unroll
        for (int j = 0; j < 8; ++j) acc[i][j] = 0.f;
    for (int kc = 0; kc < F; kc += KC) {
        #pragma unroll
        for (int p = 0; p < 2; ++p) {
            int q = tid + p * 256, r = q >> 3, kq = q & 7;
            int row = row0 + r;
            float4 v = make_float4(0.f, 0.f, 0.f, 0.f);
            if (row < n_rows) v = *(const float4*)(out + (long)row * F + kc + (kq << 2));
            a_t[kq * 4 + 0][r] = v.x; a_t[kq * 4 + 1][r] = v.y;
            a_t[kq * 4 + 2][r] = v.z; a_t[kq * 4 + 3][r] = v.w;
        }
        #pragma unroll
        for (int p = 0; p < 4; ++p) {
            int q = tid + p * 256, j = q >> 3, kq = q & 7;
            float4 v = *(const float4*)(W + (long)j * F + kc + (kq << 2));
            w_t[kq * 4 + 0][j] = v.x; w_t[kq * 4 + 1][j] = v.y;
            w_t[kq * 4 + 2][j] = v.z; w_t[kq * 4 + 3][j] = v.w;
        }
        __syncthreads();
        #pragma unroll
        for (int k = 0; k < KC; ++k) {
            float4 av = *(const float4*)&a_t[k][ty << 2];
            float4 w0 = *(const float4*)&w_t[k][tx << 2];
            float4 w1 = *(const float4*)&w_t[k][64 + (tx << 2)];
            float a4[4] = {av.x, av.y, av.z, av.w};
            float wv[8] = {w0.x, w0.y, w0.z, w0.w, w1.x, w1.y, w1.z, w1.w};
            #pragma unroll
            for (int i = 0; i < 4; ++i)
                #pragma unroll
                for (int j = 0; j < 8; ++j) acc[i][j] += a4[i] * wv[j];
        }
        __syncthreads();
    }
    float4 b0 = *(const float4*)(bias + (tx << 2));
    float4 b1 = *(const float4*)(bias + 64 + (tx << 2));
    #pragma unroll
    for (int i = 0; i < 4; ++i) {
        int row = row0 + (ty << 2) + i;
        if (row < n_rows) {
            float4 r0, r1;
            r0.x = fmaxf(acc[i][0] + b0.x, 0.f); r0.y = fmaxf(acc[i][1] + b0.y, 0.f);
            r0.z = fmaxf(acc[i][2] + b0.z, 0.f); r0.w = fmaxf(acc[i][3] + b0.w, 0.f);
            r1.x = fmaxf(acc[i][4] + b1.x, 0.f); r1.y = fmaxf(acc[i][5] + b1.y, 0.f);
            r1.z = fmaxf(acc[i][6] + b1.z, 0.f); r1.w = fmaxf(acc[i][7] + b1.w, 0.f);
            *(float4*)(out + (long)row * F + (tx << 2)) = r0;
            *(float4*)(out + (long)row * F + 64 + (tx << 2)) = r1;
        }
    }
}

extern "C" void kernel_launch(void* const* d_in, const int* in_sizes, int n_in,
                              void* d_out, int out_size, void* d_ws, size_t ws_size,
                              hipStream_t stream) {
    const float* h   = (const float*)d_in[0];
    const int*   src = (const int*)d_in[1];
    const int*   dst = (const int*)d_in[2];
    const float* W   = (const float*)d_in[3];
    const float* b   = (const float*)d_in[4];
    float* out = (float*)d_out;

    const int n_nodes = in_sizes[0] / F;
    const int n_edges = in_sizes[1];
    const int NB   = (n_nodes + NPB - 1) >> NPBS;
    const int NBLK = (n_edges + CHMAX - 1) / CHMAX;

    // ws layout: gcnt | ovf | cntmat | ebuf | hp (bf16 h@W^T) | Wb
    auto al16 = [](size_t x) { return (x + 15) & ~(size_t)15; };
    const size_t off_gcnt = 0;
    const size_t off_ovf  = al16((size_t)NB * 4);
    const size_t off_cmat = al16(off_ovf + 4 + (size_t)OVFCAP * 8);
    const size_t off_ebuf = al16(off_cmat + (size_t)NBLK * NB * 4);
    const size_t off_hp   = al16(off_ebuf + (size_t)NB * ECAP * 4);
    const size_t off_wb   = al16(off_hp + (size_t)n_nodes * F * 2);
    const size_t need     = off_wb + (size_t)F * F * 2;

    if (ws_size >= need && n_nodes > 0 && NB <= NBMAX) {
        int* gcnt = (int*)((char*)d_ws + off_gcnt);
        int* ovf  = (int*)((char*)d_ws + off_ovf);
        int* cmat = (int*)((char*)d_ws + off_cmat);
        int* ebuf = (int*)((char*)d_ws + off_ebuf);
        unsigned short* hp = (unsigned short*)((char*)d_ws + off_hp);
        unsigned short* Wb = (unsigned short*)((char*)d_ws + off_wb);

        hipMemsetAsync(ovf, 0, 4, stream);

        conv_w_kernel<<<(F * F / 4 + 255) / 256, 256, 0, stream>>>(W, Wb, F * F / 4);

        gemm_h_kernel<<<(n_nodes + 63) / 64, 256, 0, stream>>>(h, Wb, hp, n_nodes);

        if (NBLK > 0)
            count_kernel<<<NBLK, 1024, 0, stream>>>(dst, cmat, n_edges, NB);

        scan_kernel<<<NB, 256, 0, stream>>>(cmat, gcnt, NB, NBLK);

        if (NBLK > 0)
            scatter_kernel<<<NBLK, 1024, 0, stream>>>(src, dst, cmat, ebuf, ovf,
                                                      n_edges, NB);

        bucket_gather_kernel<<<NB, 1024, 0, stream>>>(hp, gcnt, ebuf, ovf, b,
                                                      out, n_nodes);
    } else {
        hipMemsetAsync(out, 0, (size_t)out_size * sizeof(float), stream);
        scatter_add_kernel<<<16384, 256, 0, stream>>>(
            h, src, dst, out, (long)n_edges * 32);
        const int gblocks = (n_nodes + BR - 1) / BR;
        gemm_bias_relu_inplace<<<gblocks, 256, 0, stream>>>(out, W, b, n_nodes);
    }
}

// Round 9
// 212.180 us; speedup vs baseline: 1.2016x; 1.0570x over previous
//
#include <hip/hip_runtime.h>

#define F      128       // feature width
#define NPB    256       // nodes per bucket
#define NPBS   8
#define NBMAX  512       // max buckets (scan width); n_nodes <= 131072 < 2^20
#define ECAP   5120      // bucket edge cap (mean 4096 @ E/N=16, +16 sigma)
#define CHMAX  4096      // edges per sort chunk
#define CH_PT  4         // CHMAX / 1024
#define OVFCAP 32768     // spill-list capacity (cold correctness path)
#define BR     64        // rows per fp32-GEMM block tile (fallback)
#define KC     32        // k-chunk (fallback GEMM)

typedef short bf16x8 __attribute__((ext_vector_type(8)));
typedef float f32x4  __attribute__((ext_vector_type(4)));

__device__ __forceinline__ unsigned short f32_to_bf16_rne(float x) {
    unsigned u = __float_as_uint(x);
    u += 0x7fffu + ((u >> 16) & 1u);
    return (unsigned short)(u >> 16);
}

// ---------------------------------------------------------------------------
// Kernel A1 (count, FUSED): block 0 converts W fp32->bf16 (64KB), zeros the
// hp pad row, resets ovf[0] (replaces conv_w dispatch + 2 memsets).  Blocks
// 1..NBLK: per-chunk bucket histogram -> cntmat row (r5 proven).
// ---------------------------------------------------------------------------
__global__ __launch_bounds__(1024) void count_kernel(
        const float* __restrict__ Wf,
        unsigned short* __restrict__ Wb,
        unsigned short* __restrict__ hp,           // only pad row touched here
        int* __restrict__ ovf,
        const int* __restrict__ dst,
        int* __restrict__ cntmat,                  // [NBLK][NB]
        int n_edges, int NB, int n_nodes) {
    const int tid = threadIdx.x;

    if (blockIdx.x == 0) {                         // prep block
        #pragma unroll
        for (int k = 0; k < 4; ++k) {
            int i = k * 1024 + tid;                // 4096 float4 = 128x128 fp32
            float4 v = *(const float4*)(Wf + 4 * (long)i);
            ushort4 o;
            o.x = f32_to_bf16_rne(v.x);
            o.y = f32_to_bf16_rne(v.y);
            o.z = f32_to_bf16_rne(v.z);
            o.w = f32_to_bf16_rne(v.w);
            *(ushort4*)(Wb + 4 * (long)i) = o;
        }
        if (tid < 64) ((int*)(hp + (size_t)n_nodes * F))[tid] = 0;  // zero row
        if (tid == 0) ovf[0] = 0;
        return;
    }

    __shared__ int hist[NBMAX];
    const int lo = (blockIdx.x - 1) * CHMAX;
    const int hi = min(n_edges, lo + CHMAX);
    for (int i = tid; i < NB; i += 1024) hist[i] = 0;
    __syncthreads();
    for (int i = lo + tid; i < hi; i += 1024)
        atomicAdd(&hist[((unsigned)dst[i]) >> NPBS], 1);
    __syncthreads();
    int* row = cntmat + (long)(blockIdx.x - 1) * NB;
    for (int i = tid; i < NB; i += 1024) row[i] = hist[i];
}

// ---------------------------------------------------------------------------
// Kernel 1: h' = h @ W^T via MFMA bf16, A staged through LDS (r8, correct).
// Algebraic reorder: segment_sum(h[src]) @ W^T == segment_sum((h@W^T)[src]).
// C layout (measured m89/m91): col=lane&15, row=quad*4+reg.
// ---------------------------------------------------------------------------
__global__ __launch_bounds__(256) void gemm_h_kernel(
        const float* __restrict__ h,
        const unsigned short* __restrict__ Wb,
        unsigned short* __restrict__ hp,          // [n+1][128] bf16 (row n = 0)
        int n_rows) {
    __shared__ unsigned short a_lds[64][136];     // +8 pad -> 272B row stride
    const int tid = threadIdx.x;
    const int r0 = blockIdx.x * 64;
    if (r0 >= n_rows) return;

    #pragma unroll
    for (int k = 0; k < 8; ++k) {                 // 2048 float4s = 64x128 fp32
        int idx = k * 256 + tid;
        int row = idx >> 5;
        int c4 = idx & 31;
        int grow = min(r0 + row, n_rows - 1);
        float4 v = *(const float4*)(h + (long)grow * F + c4 * 4);
        ushort4 o;
        o.x = f32_to_bf16_rne(v.x);
        o.y = f32_to_bf16_rne(v.y);
        o.z = f32_to_bf16_rne(v.z);
        o.w = f32_to_bf16_rne(v.w);
        *(ushort4*)&a_lds[row][c4 * 4] = o;
    }
    __syncthreads();

    const int wv = tid >> 6;
    const int lane = tid & 63;
    const int mn = lane & 15;
    const int quad = lane >> 4;
    const int m0 = r0 + wv * 16;
    if (m0 >= n_rows) return;                     // after the only sync

    bf16x8 afr[4];
    #pragma unroll
    for (int kk = 0; kk < 4; ++kk)
        afr[kk] = *(const bf16x8*)&a_lds[wv * 16 + mn][kk * 32 + quad * 8];

    f32x4 acc[8];
    #pragma unroll
    for (int t = 0; t < 8; ++t) acc[t] = (f32x4){0.f, 0.f, 0.f, 0.f};

    #pragma unroll
    for (int kk = 0; kk < 4; ++kk) {
        #pragma unroll
        for (int t = 0; t < 8; ++t) {
            const unsigned short* wp = Wb + (long)(t * 16 + mn) * F + kk * 32 + quad * 8;
            bf16x8 bfr = *(const bf16x8*)wp;
            acc[t] = __builtin_amdgcn_mfma_f32_16x16x32_bf16(afr[kk], bfr, acc[t], 0, 0, 0);
        }
    }

    #pragma unroll
    for (int t = 0; t < 8; ++t) {
        const int col = t * 16 + mn;
        #pragma unroll
        for (int r = 0; r < 4; ++r) {
            const int orow = m0 + quad * 4 + r;
            if (orow < n_rows)
                hp[(long)orow * F + col] = f32_to_bf16_rne(acc[t][r]);
        }
    }
}

// ---------------------------------------------------------------------------
// Kernel A2 (r5 verbatim): per-bucket exclusive prefix over chunks + gcnt.
// ---------------------------------------------------------------------------
__global__ __launch_bounds__(256) void scan_kernel(
        int* __restrict__ cntmat, int* __restrict__ gcnt, int NB, int NBLK) {
    __shared__ int wsum[4];
    const int b = blockIdx.x;
    const int tid = threadIdx.x;
    const int lane = tid & 63;
    const int w = tid >> 6;
    int carry = 0;
    for (int c0 = 0; c0 < NBLK; c0 += 256) {
        const int blk = c0 + tid;
        const int own = (blk < NBLK) ? cntmat[(long)blk * NB + b] : 0;
        int v = own;
        #pragma unroll
        for (int d = 1; d < 64; d <<= 1) { int u = __shfl_up(v, d); if (lane >= d) v += u; }
        if (lane == 63) wsum[w] = v;
        __syncthreads();
        if (w == 0) {
            int s = (lane < 4) ? wsum[lane] : 0;
            #pragma unroll
            for (int d = 1; d < 4; d <<= 1) { int u = __shfl_up(s, d); if (lane >= d) s += u; }
            if (lane < 4) wsum[lane] = s;
        }
        __syncthreads();
        const int excl = v - own + ((w > 0) ? wsum[w - 1] : 0) + carry;
        if (blk < NBLK) cntmat[(long)blk * NB + b] = excl;
        carry += wsum[3];
        __syncthreads();
    }
    if (tid == 0) gcnt[b] = carry;
}

// ---------------------------------------------------------------------------
// Kernel A3 (r5 verbatim): register-staged counting sort of a 4096-edge
// chunk + coalesced run flush into bucket-segmented ebuf.
// ---------------------------------------------------------------------------
__global__ __launch_bounds__(1024) void scatter_kernel(
        const int* __restrict__ src,
        const int* __restrict__ dst,
        const int* __restrict__ cntmat,
        int* __restrict__ ebuf,                    // [NB * ECAP]
        int* __restrict__ ovf,                     // [1 + 2*OVFCAP], ovf[0]=0
        int n_edges, int NB) {
    __shared__ int hist[NBMAX];
    __shared__ int dlt[NBMAX];
    __shared__ int cursor[NBMAX];
    __shared__ int sval[CHMAX];
    __shared__ unsigned short sbkt[CHMAX];
    __shared__ int wsum[16];
    const int tid = threadIdx.x;
    const int lane = tid & 63;
    const int w = tid >> 6;
    const int lo = blockIdx.x * CHMAX;
    const int hi = min(n_edges, lo + CHMAX);
    const int len = hi - lo;

    int dd[CH_PT], ss[CH_PT];
    #pragma unroll
    for (int k = 0; k < CH_PT; ++k) {
        int i = lo + k * 1024 + tid;
        bool ok = i < hi;
        dd[k] = ok ? dst[i] : -1;
        ss[k] = ok ? src[i] : 0;
    }
    for (int i = tid; i < NB; i += 1024) hist[i] = 0;
    __syncthreads();

    #pragma unroll
    for (int k = 0; k < CH_PT; ++k)
        if (dd[k] >= 0) atomicAdd(&hist[((unsigned)dd[k]) >> NPBS], 1);
    __syncthreads();

    const int own = (tid < NB) ? hist[tid] : 0;
    int v = own;
    #pragma unroll
    for (int d = 1; d < 64; d <<= 1) { int u = __shfl_up(v, d); if (lane >= d) v += u; }
    if (lane == 63) wsum[w] = v;
    __syncthreads();
    if (w == 0) {
        int s = (lane < 16) ? wsum[lane] : 0;
        #pragma unroll
        for (int d = 1; d < 16; d <<= 1) { int u = __shfl_up(s, d); if (lane >= d) s += u; }
        if (lane < 16) wsum[lane] = s;
    }
    __syncthreads();
    if (tid < NB) {
        const int excl = v - own + ((w > 0) ? wsum[w - 1] : 0);
        dlt[tid] = cntmat[(long)blockIdx.x * NB + tid] - excl;
        cursor[tid] = excl;
    }
    __syncthreads();

    #pragma unroll
    for (int k = 0; k < CH_PT; ++k)
        if (dd[k] >= 0) {
            int b = ((unsigned)dd[k]) >> NPBS;
            int p = atomicAdd(&cursor[b], 1);      // ds_add_rtn_u32
            sval[p] = ((dd[k] & (NPB - 1)) << 20) | ss[k];
            sbkt[p] = (unsigned short)b;
        }
    __syncthreads();

    for (int i = tid; i < len; i += 1024) {
        int vv = sval[i];
        int b = sbkt[i];
        int slot = i + dlt[b];
        if (slot < ECAP) {
            ebuf[(long)b * ECAP + slot] = vv;
        } else {                                   // cold correctness path
            int q = atomicAdd(&ovf[0], 1);
            if (q < OVFCAP) {
                ovf[1 + 2 * q] = (b << NPBS) | (vv >> 20);
                ovf[2 + 2 * q] = vv & 0xFFFFF;
            }
        }
    }
}

// ---------------------------------------------------------------------------
// Kernel B: per-bucket gather, QUARTER-WAVE 4-NODE scheme.  r8 evidence:
// gather plateaued 71-77us across 3 variants at 38% HBM / <50% VALU ->
// instruction-issue bound (~10 wave-instrs/edge).  Now 16 lanes x 16B = one
// 256B row per quarter-wave: each dwordx4 load covers 4 edges (4 different
// nodes), each unpack/add instr works for 4 nodes at once -> ~5.5
// wave-instrs/edge, 4x fewer loads, 16 edges in flight at 4-deep unroll.
// CSR build phases unchanged (r5/r8 proven).  Masked slots read the hp zero
// row (row n_nodes).  Each out row written exactly once.
// ---------------------------------------------------------------------------
__global__ __launch_bounds__(1024) void bucket_gather_kernel(
        const unsigned short* __restrict__ hp,     // [n_nodes+1][128], row n = 0
        const int* __restrict__ gcnt,
        const int* __restrict__ ebuf,
        const int* __restrict__ ovf,
        const float* __restrict__ bias,
        float* __restrict__ out,
        int n_nodes) {
    __shared__ int hist[NPB];
    __shared__ int ofs[NPB];
    __shared__ int cur[NPB];
    __shared__ int srt[ECAP];
    __shared__ int wsum[16];
    const int bkt = blockIdx.x;
    const int tid = threadIdx.x;
    const int lane = tid & 63;
    const int w = tid >> 6;
    const int cnt = min(gcnt[bkt], ECAP);
    const int novf = ovf[0];
    const int* eb = ebuf + (long)bkt * ECAP;

    int ev[5];                                     // 5*1024 = 5120 = ECAP
    #pragma unroll
    for (int k = 0; k < 5; ++k) {
        int i = k * 1024 + tid;
        ev[k] = (i < cnt) ? eb[i] : -1;
    }
    if (tid < NPB) hist[tid] = 0;
    __syncthreads();

    #pragma unroll
    for (int k = 0; k < 5; ++k)
        if (ev[k] >= 0) atomicAdd(&hist[((unsigned)ev[k]) >> 20], 1);
    __syncthreads();

    const int own = (tid < NPB) ? hist[tid] : 0;
    int v = own;
    #pragma unroll
    for (int d = 1; d < 64; d <<= 1) { int u = __shfl_up(v, d); if (lane >= d) v += u; }
    if (lane == 63) wsum[w] = v;
    __syncthreads();
    if (w == 0) {
        int s = (lane < 16) ? wsum[lane] : 0;
        #pragma unroll
        for (int d = 1; d < 16; d <<= 1) { int u = __shfl_up(s, d); if (lane >= d) s += u; }
        if (lane < 16) wsum[lane] = s;
    }
    __syncthreads();
    if (tid < NPB) {
        const int e = v - own + ((w > 0) ? wsum[w - 1] : 0);
        ofs[tid] = e;
        cur[tid] = e;
    }
    __syncthreads();

    #pragma unroll
    for (int k = 0; k < 5; ++k)
        if (ev[k] >= 0) {
            int p = atomicAdd(&cur[((unsigned)ev[k]) >> 20], 1);
            srt[p] = ev[k] & 0xFFFFF;
        }
    __syncthreads();

    // --- quarter-wave accumulate: group g = lane>>4 owns one node, 16 lanes
    // of the group each own 16B (8 feats) of the 256B row.
    const int li = lane & 15;
    const int g  = lane >> 4;
    const unsigned lob = (unsigned)li << 4;        // byte offset within bf16 row
    const float4 bv0 = *(const float4*)(bias + li * 8);
    const float4 bv1 = *(const float4*)(bias + li * 8 + 4);

    for (int t = 0; t < 4; ++t) {
        const int nl = w + 16 * (4 * t + g);       // this group's local node
        const int n = (bkt << NPBS) + nl;
        const int beg = ofs[nl];
        const int len = hist[nl];                  // 0 for nonexistent nodes
        int m1 = max(len, __shfl_xor(len, 16));
        const int mx = max(m1, __shfl_xor(m1, 32));

        float ax[8];
        #pragma unroll
        for (int q = 0; q < 8; ++q) ax[q] = 0.f;

        for (int i = 0; i < mx; i += 4) {          // 16 edges / wave-iter
            uint4 vv[4];
            #pragma unroll
            for (int j = 0; j < 4; ++j) {
                const int e = i + j;
                const bool val = e < len;
                const int idx = val ? (beg + e) : 0;
                int sr = srt[idx];                 // per-group bcast ds_read
                int sid = val ? sr : n_nodes;      // zero row when masked
                vv[j] = *(const uint4*)((const char*)hp +
                                        (((unsigned)sid << 8) | lob));
            }
            #pragma unroll
            for (int j = 0; j < 4; ++j) {
                ax[0] += __uint_as_float(vv[j].x << 16);
                ax[1] += __uint_as_float(vv[j].x & 0xffff0000u);
                ax[2] += __uint_as_float(vv[j].y << 16);
                ax[3] += __uint_as_float(vv[j].y & 0xffff0000u);
                ax[4] += __uint_as_float(vv[j].z << 16);
                ax[5] += __uint_as_float(vv[j].z & 0xffff0000u);
                ax[6] += __uint_as_float(vv[j].w << 16);
                ax[7] += __uint_as_float(vv[j].w & 0xffff0000u);
            }
        }

        if (novf > 0) {                            // cold spill drain
            int ne = min(novf, OVFCAP);
            for (int k = 0; k < ne; ++k) {
                if (ovf[1 + 2 * k] == n) {
                    uint4 u = *(const uint4*)((const char*)hp +
                               (((unsigned)ovf[2 + 2 * k] << 8) | lob));
                    ax[0] += __uint_as_float(u.x << 16);
                    ax[1] += __uint_as_float(u.x & 0xffff0000u);
                    ax[2] += __uint_as_float(u.y << 16);
                    ax[3] += __uint_as_float(u.y & 0xffff0000u);
                    ax[4] += __uint_as_float(u.z << 16);
                    ax[5] += __uint_as_float(u.z & 0xffff0000u);
                    ax[6] += __uint_as_float(u.w << 16);
                    ax[7] += __uint_as_float(u.w & 0xffff0000u);
                }
            }
        }

        if (n < n_nodes) {
            float4 r0, r1;
            r0.x = fmaxf(ax[0] + bv0.x, 0.f);
            r0.y = fmaxf(ax[1] + bv0.y, 0.f);
            r0.z = fmaxf(ax[2] + bv0.z, 0.f);
            r0.w = fmaxf(ax[3] + bv0.w, 0.f);
            r1.x = fmaxf(ax[4] + bv1.x, 0.f);
            r1.y = fmaxf(ax[5] + bv1.y, 0.f);
            r1.z = fmaxf(ax[6] + bv1.z, 0.f);
            r1.w = fmaxf(ax[7] + bv1.w, 0.f);
            char* ob = (char*)out + (((unsigned)n << 9) | (lob << 1));
            *(float4*)ob = r0;
            *(float4*)(ob + 16) = r1;
        }
    }
}

// ---------------------------------------------------------------------------
// Fallback tier (tiny ws or oversize graph): atomic scatter + fp32 GEMM.
// ---------------------------------------------------------------------------
__global__ void scatter_add_kernel(const float* __restrict__ h,
                                   const int* __restrict__ src,
                                   const int* __restrict__ dst,
                                   float* __restrict__ agg,
                                   long total) {
    long stride = (long)gridDim.x * blockDim.x;
    for (long i = (long)blockIdx.x * blockDim.x + threadIdx.x; i < total; i += stride) {
        int e    = (int)(i >> 5);
        int lane = (int)(i & 31);
        int s = src[e];
        int d = dst[e];
        float4 v = *(const float4*)(h + (long)s * F + (lane << 2));
        float* o = agg + (long)d * F + (lane << 2);
        unsafeAtomicAdd(o + 0, v.x);
        unsafeAtomicAdd(o + 1, v.y);
        unsafeAtomicAdd(o + 2, v.z);
        unsafeAtomicAdd(o + 3, v.w);
    }
}

__global__ __launch_bounds__(256) void gemm_bias_relu_inplace(
        float* __restrict__ out,
        const float* __restrict__ W,
        const float* __restrict__ bias,
        int n_rows) {
    __shared__ __align__(16) float a_t[KC][BR + 4];
    __shared__ __align__(16) float w_t[KC][F + 4];
    const int tid = threadIdx.x;
    const int tx = tid & 15;
    const int ty = tid >> 4;
    const int row0 = blockIdx.x * BR;
    float acc[4][8];
    #pragma unroll
    for (int i = 0; i < 4; ++i)
        #pragma unroll
        for (int j = 0; j < 8; ++j) acc[i][j] = 0.f;
    for (int kc = 0; kc < F; kc += KC) {
        #pragma unroll
        for (int p = 0; p < 2; ++p) {
            int q = tid + p * 256, r = q >> 3, kq = q & 7;
            int row = row0 + r;
            float4 v = make_float4(0.f, 0.f, 0.f, 0.f);
            if (row < n_rows) v = *(const float4*)(out + (long)row * F + kc + (kq << 2));
            a_t[kq * 4 + 0][r] = v.x; a_t[kq * 4 + 1][r] = v.y;
            a_t[kq * 4 + 2][r] = v.z; a_t[kq * 4 + 3][r] = v.w;
        }
        #pragma unroll
        for (int p = 0; p < 4; ++p) {
            int q = tid + p * 256, j = q >> 3, kq = q & 7;
            float4 v = *(const float4*)(W + (long)j * F + kc + (kq << 2));
            w_t[kq * 4 + 0][j] = v.x; w_t[kq * 4 + 1][j] = v.y;
            w_t[kq * 4 + 2][j] = v.z; w_t[kq * 4 + 3][j] = v.w;
        }
        __syncthreads();
        #pragma unroll
        for (int k = 0; k < KC; ++k) {
            float4 av = *(const float4*)&a_t[k][ty << 2];
            float4 w0 = *(const float4*)&w_t[k][tx << 2];
            float4 w1 = *(const float4*)&w_t[k][64 + (tx << 2)];
            float a4[4] = {av.x, av.y, av.z, av.w};
            float wv[8] = {w0.x, w0.y, w0.z, w0.w, w1.x, w1.y, w1.z, w1.w};
            #pragma unroll
            for (int i = 0; i < 4; ++i)
                #pragma unroll
                for (int j = 0; j < 8; ++j) acc[i][j] += a4[i] * wv[j];
        }
        __syncthreads();
    }
    float4 b0 = *(const float4*)(bias + (tx << 2));
    float4 b1 = *(const float4*)(bias + 64 + (tx << 2));
    #pragma unroll
    for (int i = 0; i < 4; ++i) {
        int row = row0 + (ty << 2) + i;
        if (row < n_rows) {
            float4 r0, r1;
            r0.x = fmaxf(acc[i][0] + b0.x, 0.f); r0.y = fmaxf(acc[i][1] + b0.y, 0.f);
            r0.z = fmaxf(acc[i][2] + b0.z, 0.f); r0.w = fmaxf(acc[i][3] + b0.w, 0.f);
            r1.x = fmaxf(acc[i][4] + b1.x, 0.f); r1.y = fmaxf(acc[i][5] + b1.y, 0.f);
            r1.z = fmaxf(acc[i][6] + b1.z, 0.f); r1.w = fmaxf(acc[i][7] + b1.w, 0.f);
            *(float4*)(out + (long)row * F + (tx << 2)) = r0;
            *(float4*)(out + (long)row * F + 64 + (tx << 2)) = r1;
        }
    }
}

extern "C" void kernel_launch(void* const* d_in, const int* in_sizes, int n_in,
                              void* d_out, int out_size, void* d_ws, size_t ws_size,
                              hipStream_t stream) {
    const float* h   = (const float*)d_in[0];
    const int*   src = (const int*)d_in[1];
    const int*   dst = (const int*)d_in[2];
    const float* W   = (const float*)d_in[3];
    const float* b   = (const float*)d_in[4];
    float* out = (float*)d_out;

    const int n_nodes = in_sizes[0] / F;
    const int n_edges = in_sizes[1];
    const int NB   = (n_nodes + NPB - 1) >> NPBS;
    const int NBLK = (n_edges + CHMAX - 1) / CHMAX;

    // ws layout: gcnt | ovf | cntmat | ebuf | hp (bf16 h@W^T, +1 zero row) | Wb
    auto al16 = [](size_t x) { return (x + 15) & ~(size_t)15; };
    const size_t off_gcnt = 0;
    const size_t off_ovf  = al16((size_t)NB * 4);
    const size_t off_cmat = al16(off_ovf + 4 + (size_t)OVFCAP * 8);
    const size_t off_ebuf = al16(off_cmat + (size_t)(NBLK > 0 ? NBLK : 1) * NB * 4);
    const size_t off_hp   = al16(off_ebuf + (size_t)NB * ECAP * 4);
    const size_t off_wb   = al16(off_hp + (size_t)(n_nodes + 1) * F * 2);
    const size_t need     = off_wb + (size_t)F * F * 2;

    if (ws_size >= need && n_nodes > 0 && NB <= NBMAX) {
        int* gcnt = (int*)((char*)d_ws + off_gcnt);
        int* ovf  = (int*)((char*)d_ws + off_ovf);
        int* cmat = (int*)((char*)d_ws + off_cmat);
        int* ebuf = (int*)((char*)d_ws + off_ebuf);
        unsigned short* hp = (unsigned short*)((char*)d_ws + off_hp);
        unsigned short* Wb = (unsigned short*)((char*)d_ws + off_wb);

        count_kernel<<<NBLK + 1, 1024, 0, stream>>>(
            W, Wb, hp, ovf, dst, cmat, n_edges, NB, n_nodes);

        gemm_h_kernel<<<(n_nodes + 63) / 64, 256, 0, stream>>>(h, Wb, hp, n_nodes);

        scan_kernel<<<NB, 256, 0, stream>>>(cmat, gcnt, NB, NBLK);

        if (NBLK > 0)
            scatter_kernel<<<NBLK, 1024, 0, stream>>>(src, dst, cmat, ebuf, ovf,
                                                      n_edges, NB);

        bucket_gather_kernel<<<NB, 1024, 0, stream>>>(hp, gcnt, ebuf, ovf, b,
                                                      out, n_nodes);
    } else {
        hipMemsetAsync(out, 0, (size_t)out_size * sizeof(float), stream);
        scatter_add_kernel<<<16384, 256, 0, stream>>>(
            h, src, dst, out, (long)n_edges * 32);
        const int gblocks = (n_nodes + BR - 1) / BR;
        gemm_bias_relu_inplace<<<gblocks, 256, 0, stream>>>(out, W, b, n_nodes);
    }
}